// Round 2
// baseline (10150.118 us; speedup 1.0000x reference)
//
#include <hip/hip_runtime.h>
#include <stdint.h>

#define T_LEN 4096
#define HID   400
#define G4    1600
#define KDIM  300
#define STACKN 32

__device__ __forceinline__ float fsig(float x){ return 1.f/(1.f + __expf(-x)); }
__device__ __forceinline__ float ftanh(float x){ float e = __expf(2.f*x); return 1.f - 2.f/(e+1.f); }

// Pipelined tagged poll: keep 4 outstanding loads, check the oldest.
// Sampling period ~L/4 instead of ~L -> cuts detection staleness.
__device__ __forceinline__ unsigned long long poll_u64(const unsigned long long* src, unsigned tag){
  unsigned long long x0 = __hip_atomic_load(src, __ATOMIC_RELAXED, __HIP_MEMORY_SCOPE_AGENT);
  unsigned long long x1 = __hip_atomic_load(src, __ATOMIC_RELAXED, __HIP_MEMORY_SCOPE_AGENT);
  unsigned long long x2 = __hip_atomic_load(src, __ATOMIC_RELAXED, __HIP_MEMORY_SCOPE_AGENT);
  unsigned long long x3 = __hip_atomic_load(src, __ATOMIC_RELAXED, __HIP_MEMORY_SCOPE_AGENT);
  while ((unsigned)(x0 >> 32) != tag){
    x0 = x1; x1 = x2; x2 = x3;
    x3 = __hip_atomic_load(src, __ATOMIC_RELAXED, __HIP_MEMORY_SCOPE_AGENT);
  }
  return x0;
}
__device__ __forceinline__ float poll_val(const unsigned long long* src, unsigned tag){
  union{unsigned u; float f;} cv; cv.u = (unsigned)poll_u64(src, tag);
  return cv.f;
}

// ---------------- layer-0 xg GEMM with fused embedding gather (K=150, f32) ----------------
__global__ void __launch_bounds__(256) kgemm0(
    const int* __restrict__ xma, const int* __restrict__ xcpc, const int* __restrict__ xr,
    const float* __restrict__ em, const float* __restrict__ ec, const float* __restrict__ er,
    const float* __restrict__ W, const float* __restrict__ b1, const float* __restrict__ b2,
    float* __restrict__ XG)
{
  __shared__ float xs[8*152];
  const int t0 = blockIdx.x*8;
  const int tid = threadIdx.x;
  for (int idx = tid; idx < 8*150; idx += 256){
    int tt = idx / 150, k = idx - tt*150;
    int t = t0 + tt;
    float v;
    if (k < 50)       v = em[(size_t)xma[t]*50 + k];
    else if (k < 100) v = ec[(size_t)xcpc[t]*50 + (k-50)];
    else              v = er[(size_t)xr[t]*50 + (k-100)];
    xs[tt*152 + k] = v;
  }
  __syncthreads();
  int r = blockIdx.y*256 + tid;
  if (r >= G4) return;
  float acc[8];
  #pragma unroll
  for (int i=0;i<8;i++) acc[i]=0.f;
  const float2* wr = (const float2*)(W + (size_t)r*150);
  for (int k2=0;k2<75;k2++){
    float2 w = wr[k2];
    int k = 2*k2;
    #pragma unroll
    for (int tt=0;tt<8;tt++)
      acc[tt] += w.x*xs[tt*152+k] + w.y*xs[tt*152+k+1];
  }
  float bb = b1[r] + b2[r];
  #pragma unroll
  for (int tt=0;tt<8;tt++)
    XG[(size_t)(t0+tt)*G4 + r] = acc[tt] + bb;
}

// ================== fused 2-layer pipelined LSTM scan ==================
// Grid 128, role = blockIdx & 7  (native round-robin => each role lives on one XCD):
//   role 0: layer-0 recurrence (16 WGs)   role 1: FF xg1 (16 WGs)
//   role 2: layer-1 recurrence -> RN (16 WGs)   roles 3-7: exit.
// Handshake: tagged u64 {tag hi32, f32 lo32}, relaxed agent atomics, depth-8 slots.
// Back-pressure: role-0 publishes h(t+1) (destroying ring tag t-7) only after
// confirming role-2 completed iter t-7 (hbufB tag t-6 present). Role-2 consumes
// role-1's output, so this single throttle bounds lag on BOTH rings at <=7:
// worst case is throttling, never tag-overwrite deadlock. Steady-state lag ~2-3
// so the check is a first-try hit; its 4 loads issue at loop-top, checked after
// barrier B -> zero-latency when not throttling.
__global__ void __launch_bounds__(512,1) kpipe(
    const float* __restrict__ XG0,
    const float* __restrict__ Whh0, const float* __restrict__ Whh1,
    const float* __restrict__ Wih1, const float* __restrict__ bih1,
    const float* __restrict__ bhh1,
    float* __restrict__ RN,
    unsigned long long* hbufA, unsigned long long* hbufB,
    unsigned long long* gbuf, int T)
{
  const int role = blockIdx.x & 7;
  if (role > 2) return;
  const int sub = blockIdx.x >> 3;       // 0..15
  const int tid = threadIdx.x;
  const int row_local = tid >> 2;        // 0..127 (100 used)
  const int part = tid & 3;              // k-slice of 100
  const bool mat = (tid < 400);
  const bool ew  = (tid >= 448 && tid < 473);  // dedicated wave-7 elementwise lanes
  const int  ej  = tid - 448;            // 0..24 for ew lanes

  __shared__ float lds_h[HID];
  __shared__ float lds_g[100];

  if (role == 0){
    // ---------- layer-0 recurrence ----------
    const int w = sub;
    float wreg[100];
    if (mat){
      int gate = row_local/25, jj = row_local%25;
      int row = gate*400 + w*25 + jj;
      const float4* wr = (const float4*)(Whh0 + (size_t)row*HID) + part*25;
      #pragma unroll
      for (int i=0;i<25;i++){
        float4 v = wr[i];
        wreg[4*i]=v.x; wreg[4*i+1]=v.y; wreg[4*i+2]=v.z; wreg[4*i+3]=v.w;
      }
    }
    const int j = w*25 + ej;
    float c = 0.f;
    for (int t=0; t<T; t++){
      float xgi=0.f, xgf=0.f, xgg=0.f, xgo=0.f;
      unsigned long long th0=0, th1=0, th2=0, th3=0;
      const unsigned long long* thp = 0;
      if (ew){
        const float* xrw = XG0 + (size_t)t*G4;
        xgi = xrw[j]; xgf = xrw[HID+j]; xgg = xrw[2*HID+j]; xgo = xrw[3*HID+j];
        if (t >= 7){   // throttle probe: role-2 done iter t-7?  (4 loads in flight)
          thp = hbufB + (size_t)((t-6)&7)*HID + j;
          th0 = __hip_atomic_load(thp, __ATOMIC_RELAXED, __HIP_MEMORY_SCOPE_AGENT);
          th1 = __hip_atomic_load(thp, __ATOMIC_RELAXED, __HIP_MEMORY_SCOPE_AGENT);
          th2 = __hip_atomic_load(thp, __ATOMIC_RELAXED, __HIP_MEMORY_SCOPE_AGENT);
          th3 = __hip_atomic_load(thp, __ATOMIC_RELAXED, __HIP_MEMORY_SCOPE_AGENT);
        }
      }
      if (mat){
        float hv = 0.f;
        if (t > 0) hv = poll_val(hbufA + (size_t)(t&7)*HID + tid, (unsigned)t);
        lds_h[tid] = hv;
      }
      __syncthreads();                       // A: lds_h ready
      float sum = 0.f;
      if (mat){
        const float4* hp = (const float4*)(lds_h + part*100);
        #pragma unroll
        for (int i=0;i<25;i++){
          float4 h4 = hp[i];
          sum += wreg[4*i]*h4.x + wreg[4*i+1]*h4.y + wreg[4*i+2]*h4.z + wreg[4*i+3]*h4.w;
        }
      }
      sum += __shfl_xor(sum, 1);
      sum += __shfl_xor(sum, 2);
      if (mat && part==0) lds_g[row_local] = sum;
      __syncthreads();                       // B: lds_g ready; mat done with lds_h
      if (ew){
        float gi = xgi + lds_g[ej];
        float gf = xgf + lds_g[25+ej];
        float gg = xgg + lds_g[50+ej];
        float go = xgo + lds_g[75+ej];
        float si = fsig(gi), sf = fsig(gf), so = fsig(go), tg = ftanh(gg);
        c = sf*c + si*tg;
        float h = so*ftanh(c);
        if (t >= 7){                         // consume throttle probe (steady: hit)
          unsigned want = (unsigned)(t-6);
          while ((unsigned)(th0 >> 32) != want){
            th0 = th1; th1 = th2; th2 = th3;
            th3 = __hip_atomic_load(thp, __ATOMIC_RELAXED, __HIP_MEMORY_SCOPE_AGENT);
          }
        }
        union{unsigned u; float f;} cv; cv.f = h;
        unsigned long long pk = ((unsigned long long)(unsigned)(t+1) << 32) | (unsigned long long)cv.u;
        __hip_atomic_store(hbufA + (size_t)((t+1)&7)*HID + j, pk,
                           __ATOMIC_RELAXED, __HIP_MEMORY_SCOPE_AGENT);
      }
      // no third barrier: other waves proceed straight to polling t+1
    }
  } else if (role == 1){
    // ---------- FF: xg1_t = Wih1(own 100 rows) @ h0_t + bih1 + bhh1 ----------
    const int f = sub;
    float wreg[100];
    float bias = 0.f;
    int grow = 0;
    if (mat){
      int gate = row_local/25, jj = row_local%25;
      grow = gate*400 + f*25 + jj;
      const float4* wr = (const float4*)(Wih1 + (size_t)grow*HID) + part*25;
      #pragma unroll
      for (int i=0;i<25;i++){
        float4 v = wr[i];
        wreg[4*i]=v.x; wreg[4*i+1]=v.y; wreg[4*i+2]=v.z; wreg[4*i+3]=v.w;
      }
      if (part==0) bias = bih1[grow] + bhh1[grow];
    }
    for (int t=0; t<T; t++){
      if (mat)
        lds_h[tid] = poll_val(hbufA + (size_t)((t+1)&7)*HID + tid, (unsigned)(t+1));
      __syncthreads();                       // A
      float sum = 0.f;
      if (mat){
        const float4* hp = (const float4*)(lds_h + part*100);
        #pragma unroll
        for (int i=0;i<25;i++){
          float4 h4 = hp[i];
          sum += wreg[4*i]*h4.x + wreg[4*i+1]*h4.y + wreg[4*i+2]*h4.z + wreg[4*i+3]*h4.w;
        }
      }
      sum += __shfl_xor(sum, 1);
      sum += __shfl_xor(sum, 2);
      if (mat && part==0){
        union{unsigned u; float f;} cv; cv.f = sum + bias;
        unsigned long long pk = ((unsigned long long)(unsigned)(t+1) << 32) | (unsigned long long)cv.u;
        __hip_atomic_store(gbuf + (size_t)((t+1)&7)*G4 + grow, pk,
                           __ATOMIC_RELAXED, __HIP_MEMORY_SCOPE_AGENT);
      }
      __syncthreads();                       // B: protect lds_h refill
    }
  } else {
    // ---------- layer-1 recurrence ----------
    const int l = sub;
    float wreg[100];
    if (mat){
      int gate = row_local/25, jj = row_local%25;
      int row = gate*400 + l*25 + jj;
      const float4* wr = (const float4*)(Whh1 + (size_t)row*HID) + part*25;
      #pragma unroll
      for (int i=0;i<25;i++){
        float4 v = wr[i];
        wreg[4*i]=v.x; wreg[4*i+1]=v.y; wreg[4*i+2]=v.z; wreg[4*i+3]=v.w;
      }
    }
    const int j = l*25 + ej;
    float c = 0.f;
    for (int t=0; t<T; t++){
      if (mat){
        float hv = 0.f;
        if (t > 0) hv = poll_val(hbufB + (size_t)(t&7)*HID + tid, (unsigned)t);
        lds_h[tid] = hv;
      }
      __syncthreads();                       // A
      // ew: poll the 4 gate inputs (independent addrs, concurrent) in the
      // matvec shadow -- off the barrier-A critical path, needed only after B.
      float xg0=0.f, xg1v=0.f, xg2=0.f, xg3=0.f;
      if (ew){
        const unsigned long long* gb = gbuf + (size_t)((t+1)&7)*G4 + j;
        unsigned want = (unsigned)(t+1);
        unsigned long long v0, v1, v2, v3;
        for (;;){
          v0 = __hip_atomic_load(gb,        __ATOMIC_RELAXED, __HIP_MEMORY_SCOPE_AGENT);
          v1 = __hip_atomic_load(gb + 400,  __ATOMIC_RELAXED, __HIP_MEMORY_SCOPE_AGENT);
          v2 = __hip_atomic_load(gb + 800,  __ATOMIC_RELAXED, __HIP_MEMORY_SCOPE_AGENT);
          v3 = __hip_atomic_load(gb + 1200, __ATOMIC_RELAXED, __HIP_MEMORY_SCOPE_AGENT);
          if (((unsigned)(v0>>32)==want) & ((unsigned)(v1>>32)==want) &
              ((unsigned)(v2>>32)==want) & ((unsigned)(v3>>32)==want)) break;
        }
        union{unsigned u; float f;} c0,c1,c2,c3;
        c0.u=(unsigned)v0; c1.u=(unsigned)v1; c2.u=(unsigned)v2; c3.u=(unsigned)v3;
        xg0=c0.f; xg1v=c1.f; xg2=c2.f; xg3=c3.f;
      }
      float sum = 0.f;
      if (mat){
        const float4* hp = (const float4*)(lds_h + part*100);
        #pragma unroll
        for (int i=0;i<25;i++){
          float4 h4 = hp[i];
          sum += wreg[4*i]*h4.x + wreg[4*i+1]*h4.y + wreg[4*i+2]*h4.z + wreg[4*i+3]*h4.w;
        }
      }
      sum += __shfl_xor(sum, 1);
      sum += __shfl_xor(sum, 2);
      if (mat && part==0) lds_g[row_local] = sum;
      __syncthreads();                       // B
      if (ew){
        float gi = xg0  + lds_g[ej];
        float gf = xg1v + lds_g[25+ej];
        float gg = xg2  + lds_g[50+ej];
        float go = xg3  + lds_g[75+ej];
        float si = fsig(gi), sf = fsig(gf), so = fsig(go), tg = ftanh(gg);
        c = sf*c + si*tg;
        float h = so*ftanh(c);
        union{unsigned u; float f;} cv; cv.f = h;
        unsigned long long pk = ((unsigned long long)(unsigned)(t+1) << 32) | (unsigned long long)cv.u;
        __hip_atomic_store(hbufB + (size_t)((t+1)&7)*HID + j, pk,
                           __ATOMIC_RELAXED, __HIP_MEMORY_SCOPE_AGENT);
        RN[(size_t)t*HID + j] = h;
      }
    }
  }
}

// ---------------- rtoken = RN @ fcW.T + fcb  (f32) ----------------
__global__ void __launch_bounds__(256) krtoken(
    const float* __restrict__ RN, const float* __restrict__ fcW,
    const float* __restrict__ fcb, float* __restrict__ out)
{
  __shared__ float xs[8*400];
  const int t0 = blockIdx.x*8;
  const int tid = threadIdx.x;
  for (int idx = tid; idx < 8*400; idx += 256)
    xs[idx] = RN[(size_t)t0*400 + idx];
  __syncthreads();
  if (tid >= 150) return;
  float acc[8];
  #pragma unroll
  for (int i=0;i<8;i++) acc[i]=0.f;
  const float4* wr = (const float4*)(fcW + (size_t)tid*400);
  for (int k4=0;k4<100;k4++){
    float4 w = wr[k4];
    #pragma unroll
    for (int tt=0;tt<8;tt++){
      const float4 x4 = *(const float4*)(xs + tt*400 + 4*k4);
      acc[tt] += w.x*x4.x + w.y*x4.y + w.z*x4.z + w.w*x4.w;
    }
  }
  float bb = fcb[tid];
  #pragma unroll
  for (int tt=0;tt<8;tt++)
    out[(size_t)(t0+tt)*150 + tid] = acc[tt] + bb;
}

// ---------------- per-t context scalar: v[t] = softmax0(actW@rnn+actb) * sigmoid(D@rnn) ----
__global__ void kfinal(const float* __restrict__ RN, const float* __restrict__ actW,
                       const float* __restrict__ actb, const float* __restrict__ Dp,
                       float* __restrict__ vbuf)
{
  int t = blockIdx.x, l = threadIdx.x;
  const float* r = RN + (size_t)t*HID;
  float s0=0.f, s1=0.f, s2=0.f, sd=0.f;
  for (int k=l; k<HID; k+=64){
    float rv = r[k];
    s0 += actW[k]*rv;
    s1 += actW[400+k]*rv;
    s2 += actW[800+k]*rv;
    sd += Dp[k]*rv;
  }
  #pragma unroll
  for (int o=1;o<64;o<<=1){
    s0 += __shfl_xor(s0,o); s1 += __shfl_xor(s1,o);
    s2 += __shfl_xor(s2,o); sd += __shfl_xor(sd,o);
  }
  if (l==0){
    s0 += actb[0]; s1 += actb[1]; s2 += actb[2];
    float m = fmaxf(s0, fmaxf(s1, s2));
    float e0 = __expf(s0-m), e1 = __expf(s1-m), e2 = __expf(s2-m);
    float p0 = e0/(e0+e1+e2);
    vbuf[t] = p0 * fsig(sd);
  }
}

// ---------------- context write: zero everything, slot0 = v[t] broadcast (f32) ----------------
// LAST kernel: deterministically overwrites the whole ctx region (which doubled as scratch).
__global__ void kctx(const float* __restrict__ vbuf, uint4* __restrict__ ctx, int n16){
  int i = blockIdx.x*256 + threadIdx.x;
  int stride = gridDim.x*256;
  for (; i<n16; i+=stride){
    int t = i / 3200;
    int p = i - t*3200;
    uint4 z;
    if (p < 100){
      float v = vbuf[t];
      union{float f; uint32_t u;} cv; cv.f = v;
      z.x = z.y = z.z = z.w = cv.u;
    } else {
      z.x = z.y = z.z = z.w = 0u;
    }
    ctx[i] = z;
  }
}

// ---------------- key LSTM (1 step, h0=c0=0 so key_Whh is dead) + fc (f32) ----------------
__global__ void __launch_bounds__(512) kkey(
    const float* __restrict__ RN, const float* __restrict__ Wih,
    const float* __restrict__ bih, const float* __restrict__ bhh,
    const float* __restrict__ fcW, const float* __restrict__ fcb,
    float* __restrict__ out)
{
  __shared__ float rh[HID];
  __shared__ float gk[4*KDIM];
  __shared__ float hk[KDIM];
  int tid = threadIdx.x;
  if (tid < HID) rh[tid] = RN[(size_t)(T_LEN-1)*HID + tid];
  __syncthreads();
  for (int r = tid; r < 4*KDIM; r += 512){
    const float4* wr = (const float4*)(Wih + (size_t)r*HID);
    float acc = 0.f;
    for (int k4=0;k4<100;k4++){
      float4 w = wr[k4];
      const float4 x4 = *(const float4*)(rh + 4*k4);
      acc += w.x*x4.x + w.y*x4.y + w.z*x4.z + w.w*x4.w;
    }
    gk[r] = acc + bih[r] + bhh[r];
  }
  __syncthreads();
  if (tid < KDIM){
    float gi = gk[tid], gg = gk[2*KDIM+tid], go = gk[3*KDIM+tid];
    float cc = fsig(gi)*ftanh(gg);        // c0 = 0 -> forget-gate term vanishes
    hk[tid] = fsig(go)*ftanh(cc);
  }
  __syncthreads();
  if (tid < HID){
    const float4* wr = (const float4*)(fcW + (size_t)tid*KDIM);
    float acc = 0.f;
    for (int k4=0;k4<75;k4++){
      float4 w = wr[k4];
      const float4 x4 = *(const float4*)(hk + 4*k4);
      acc += w.x*x4.x + w.y*x4.y + w.z*x4.z + w.w*x4.w;
    }
    out[tid] = acc + fcb[tid];
  }
}

extern "C" void kernel_launch(void* const* d_in, const int* in_sizes, int n_in,
                              void* d_out, int out_size, void* d_ws, size_t ws_size,
                              hipStream_t stream)
{
  (void)in_sizes; (void)n_in; (void)ws_size;
  const int*   xr   = (const int*)d_in[0];
  const int*   xcpc = (const int*)d_in[1];
  const int*   xma  = (const int*)d_in[2];
  const float* em   = (const float*)d_in[3];
  const float* ec   = (const float*)d_in[4];
  const float* er   = (const float*)d_in[5];
  const float* Wih0 = (const float*)d_in[6];
  const float* Whh0 = (const float*)d_in[7];
  const float* bih0 = (const float*)d_in[8];
  const float* bhh0 = (const float*)d_in[9];
  const float* Wih1 = (const float*)d_in[10];
  const float* Whh1 = (const float*)d_in[11];
  const float* bih1 = (const float*)d_in[12];
  const float* bhh1 = (const float*)d_in[13];
  const float* fcW  = (const float*)d_in[14];
  const float* fcb  = (const float*)d_in[15];
  const float* actW = (const float*)d_in[16];
  const float* actb = (const float*)d_in[17];
  const float* Dp   = (const float*)d_in[18];
  const float* kWih = (const float*)d_in[19];
  /* d_in[20] key_Whh unused: h0 = 0 for the single key step */
  const float* kbih = (const float*)d_in[21];
  const float* kbhh = (const float*)d_in[22];
  const float* kfcW = (const float*)d_in[23];
  const float* kfcb = (const float*)d_in[24];

  // ---- vbuf stays in ws (kctx both reads vbuf and rewrites the ctx region) ----
  float* vbuf = (float*)d_ws;                           // 16 KB

  // ---- large scratch + handshake bufs in TAIL of d_out's ctx region (kctx rewrites last) ----
  float* out = (float*)d_out;
  char*  ob  = (char*)d_out;
  size_t total = (size_t)out_size * 4;                  // 212,174,400 bytes
  float* XG0 = (float*)(ob + total - 26214400);         // 4096*1600 f32
  float* RN  = (float*)(ob + total - 32768000);         // 4096*400 f32
  char*  ctl = ob + total - 32768000 - 262144;          // control block (256 KB reserve)
  unsigned long long* hbufA = (unsigned long long*)(ctl);          // 8*400*8 = 25,600 B
  unsigned long long* hbufB = (unsigned long long*)(ctl + 25600);  // 25,600 B
  unsigned long long* gbuf  = (unsigned long long*)(ctl + 51200);  // 8*1600*8 = 102,400 B

  float* rtok = out;                 // 4096*150
  float* ktok = out + 614400;        // 400
  uint4* ctxp = (uint4*)(ob + 614800u*4u);              // ctx region, 209,715,200 B
  int n16 = (int)((total - 614800u*4u) >> 4);           // 13,107,200

  dim3 gg(T_LEN/8, 7);
  kgemm0<<<gg,256,0,stream>>>(xma, xcpc, xr, em, ec, er, Wih0, bih0, bhh0, XG0);
  kpipe<<<128,512,0,stream>>>(XG0, Whh0, Whh1, Wih1, bih1, bhh1, RN,
                              hbufA, hbufB, gbuf, T_LEN);
  krtoken<<<T_LEN/8,256,0,stream>>>(RN, fcW, fcb, rtok);
  kkey<<<1,512,0,stream>>>(RN, kWih, kbih, kbhh, kfcW, kfcb, ktok);
  kfinal<<<T_LEN,64,0,stream>>>(RN, actW, actb, Dp, vbuf);
  kctx<<<2048,256,0,stream>>>(vbuf, ctxp, n16);
}